// Round 2
// baseline (287.688 us; speedup 1.0000x reference)
//
#include <hip/hip_runtime.h>
#include <math.h>

#define NFRAMES 6
#define NBOX    1000000
#define TOTAL   (NFRAMES * NBOX)

// W = 1.85 + 0.5, H = 4.084 + 0.5
#define HALF_W  (2.35f * 0.5f)
#define HALF_H  (4.584f * 0.5f)

__global__ void zero_out_kernel(float* out) { out[0] = 0.0f; }

__global__ __launch_bounds__(256) void CollisionLoss_55327768708655_kernel(
    const float* __restrict__ traj,     // (1, F, 2)
    const float* __restrict__ gt,       // (1, F, 3)
    const float* __restrict__ corners,  // (F, N, 4, 2)
    const int* __restrict__ mask,       // (F, N) bool stored as int32 by harness
    float* __restrict__ out)
{
    // --- per-block: compute the 6 frame AABBs into LDS (cost: negligible) ---
    __shared__ float s_xa1[NFRAMES], s_ya1[NFRAMES], s_xa2[NFRAMES], s_ya2[NFRAMES];
    if (threadIdx.x < NFRAMES) {
        int f = threadIdx.x;
        float x  = traj[f * 2 + 0];
        float y  = traj[f * 2 + 1];
        float th = gt[f * 3 + 2];
        float c = cosf(th), s = sinf(th);
        // AABB half-extents of a rotated WxH rectangle
        float ex = fabsf(c) * HALF_W + fabsf(s) * HALF_H;
        float ey = fabsf(s) * HALF_W + fabsf(c) * HALF_H;
        s_xa1[f] = x + ex;  s_xa2[f] = x - ex;
        s_ya1[f] = y + ey;  s_ya2[f] = y - ey;
    }
    __syncthreads();

    // --- grid-stride over all 6M boxes: 32B/elem coalesced float4 loads ---
    float acc = 0.0f;
    int stride = gridDim.x * blockDim.x;
    for (int i = blockIdx.x * blockDim.x + threadIdx.x; i < TOTAL; i += stride) {
        const float4* p = (const float4*)(corners + (size_t)i * 8);
        float4 a = p[0];  // c0.x c0.y c1.x c1.y
        float4 b = p[1];  // c2.x c2.y c3.x c3.y
        float xb1 = fmaxf(fmaxf(a.x, a.z), fmaxf(b.x, b.z));
        float xb2 = fminf(fminf(a.x, a.z), fminf(b.x, b.z));
        float yb1 = fmaxf(fmaxf(a.y, a.w), fmaxf(b.y, b.w));
        float yb2 = fminf(fminf(a.y, a.w), fminf(b.y, b.w));

        int f = i / NBOX;  // frame index (compiler turns into magic-mul)
        float w = fminf(s_xa1[f], xb1) - fmaxf(s_xa2[f], xb2);
        float h = fminf(s_ya1[f], yb1) - fmaxf(s_ya2[f], yb2);
        w = fmaxf(w, 0.0f);
        h = fmaxf(h, 0.0f);
        float v = w * h;
        acc += mask[i] ? v : 0.0f;
    }

    // --- wave-64 shuffle reduce -> LDS -> one atomic per block ---
    #pragma unroll
    for (int off = 32; off > 0; off >>= 1)
        acc += __shfl_down(acc, off, 64);

    __shared__ float s_part[4];  // 256 threads / 64 lanes
    int lane = threadIdx.x & 63;
    int wave = threadIdx.x >> 6;
    if (lane == 0) s_part[wave] = acc;
    __syncthreads();
    if (threadIdx.x == 0) {
        float t = s_part[0] + s_part[1] + s_part[2] + s_part[3];
        atomicAdd(out, t);  // WEIGHT == 1.0
    }
}

extern "C" void kernel_launch(void* const* d_in, const int* in_sizes, int n_in,
                              void* d_out, int out_size, void* d_ws, size_t ws_size,
                              hipStream_t stream) {
    const float* traj     = (const float*)d_in[0];  // sdc_traj_all (1,F,2)
    const float* gt       = (const float*)d_in[1];  // sdc_planning_gt (1,F,3)
    // d_in[2] = sdc_planning_gt_mask — unused by the reference
    const float* corners  = (const float*)d_in[3];  // future_gt_corners (F,N,4,2)
    const int* mask       = (const int*)d_in[4];    // box_mask (F,N) bool -> int32
    float* out = (float*)d_out;

    // d_out is poisoned to 0xAA before every call — zero it first (stream-ordered).
    zero_out_kernel<<<1, 1, 0, stream>>>(out);

    // 2048 blocks x 256 threads: 8 blocks/CU on 256 CUs, ~11 elems/thread.
    CollisionLoss_55327768708655_kernel<<<2048, 256, 0, stream>>>(traj, gt, corners, mask, out);
}

// Round 5
// 287.604 us; speedup vs baseline: 1.0003x; 1.0003x over previous
//
#include <hip/hip_runtime.h>
#include <math.h>

#define NFRAMES 6
#define NBOX    1000000
#define TOTAL   (NFRAMES * NBOX)

#define BPT     4                           // boxes per thread (NBOX % 4 == 0 -> no frame-boundary crossing within a thread)
#define NTHREADS (TOTAL / BPT)              // 1,500,000
#define BLOCK   256
#define NBLOCKS ((NTHREADS + BLOCK - 1) / BLOCK)   // 5860

// W = 1.85 + 0.5, H = 4.084 + 0.5
#define HALF_W  (2.35f * 0.5f)
#define HALF_H  (4.584f * 0.5f)

__global__ __launch_bounds__(BLOCK) void CollisionLoss_55327768708655_kernel(
    const float* __restrict__ traj,     // (1, F, 2)
    const float* __restrict__ gt,       // (1, F, 3)
    const float* __restrict__ corners,  // (F, N, 4, 2)
    const int*   __restrict__ mask,     // (F, N) bool stored as int32
    float* __restrict__ partials)       // NBLOCKS floats in d_ws
{
    // --- per-block: 6 frame AABBs into LDS as float4 {xa1, ya1, xa2, ya2} ---
    __shared__ float4 s_frame[NFRAMES];
    if (threadIdx.x < NFRAMES) {
        int f = threadIdx.x;
        float x  = traj[f * 2 + 0];
        float y  = traj[f * 2 + 1];
        float th = gt[f * 3 + 2];
        float c = cosf(th), s = sinf(th);
        float ex = fabsf(c) * HALF_W + fabsf(s) * HALF_H;  // AABB half-extents of rotated WxH rect
        float ey = fabsf(s) * HALF_W + fabsf(c) * HALF_H;
        s_frame[f] = make_float4(x + ex, y + ey, x - ex, y - ey);
    }
    __syncthreads();

    float acc = 0.0f;
    int tid = blockIdx.x * BLOCK + threadIdx.x;
    if (tid < NTHREADS) {
        // 4 boxes per thread: 8 independent dwordx4 corner loads + 1 dwordx4 mask load
        const float4* p = (const float4*)corners + (size_t)tid * (2 * BPT);
        float4 A[8];
        #pragma unroll
        for (int j = 0; j < 8; ++j) A[j] = p[j];
        int4 m = ((const int4*)mask)[tid];

        int f = (tid * BPT) / NBOX;         // all 4 boxes in the same frame (NBOX % 4 == 0)
        float4 fr = s_frame[f];             // one ds_read_b128

        int M[4] = {m.x, m.y, m.z, m.w};
        #pragma unroll
        for (int j = 0; j < BPT; ++j) {
            float4 a = A[2 * j + 0];        // c0.x c0.y c1.x c1.y
            float4 b = A[2 * j + 1];        // c2.x c2.y c3.x c3.y
            float xb1 = fmaxf(fmaxf(a.x, a.z), fmaxf(b.x, b.z));
            float xb2 = fminf(fminf(a.x, a.z), fminf(b.x, b.z));
            float yb1 = fmaxf(fmaxf(a.y, a.w), fmaxf(b.y, b.w));
            float yb2 = fminf(fminf(a.y, a.w), fminf(b.y, b.w));
            float w = fminf(fr.x, xb1) - fmaxf(fr.z, xb2);
            float h = fminf(fr.y, yb1) - fmaxf(fr.w, yb2);
            float v = fmaxf(w, 0.0f) * fmaxf(h, 0.0f);
            acc += M[j] ? v : 0.0f;
        }
    }

    // --- wave-64 shuffle reduce -> LDS -> one plain store per block ---
    #pragma unroll
    for (int off = 32; off > 0; off >>= 1)
        acc += __shfl_down(acc, off, 64);

    __shared__ float s_part[BLOCK / 64];
    int lane = threadIdx.x & 63;
    int wave = threadIdx.x >> 6;
    if (lane == 0) s_part[wave] = acc;
    __syncthreads();
    if (threadIdx.x == 0)
        partials[blockIdx.x] = s_part[0] + s_part[1] + s_part[2] + s_part[3];
}

__global__ __launch_bounds__(BLOCK) void finalize_kernel(
    const float* __restrict__ partials, float* __restrict__ out)
{
    float acc = 0.0f;
    for (int i = threadIdx.x; i < NBLOCKS; i += BLOCK)
        acc += partials[i];
    #pragma unroll
    for (int off = 32; off > 0; off >>= 1)
        acc += __shfl_down(acc, off, 64);
    __shared__ float s_part[BLOCK / 64];
    int lane = threadIdx.x & 63;
    int wave = threadIdx.x >> 6;
    if (lane == 0) s_part[wave] = acc;
    __syncthreads();
    if (threadIdx.x == 0)
        out[0] = s_part[0] + s_part[1] + s_part[2] + s_part[3];  // WEIGHT == 1.0
}

extern "C" void kernel_launch(void* const* d_in, const int* in_sizes, int n_in,
                              void* d_out, int out_size, void* d_ws, size_t ws_size,
                              hipStream_t stream) {
    const float* traj     = (const float*)d_in[0];  // sdc_traj_all (1,F,2)
    const float* gt       = (const float*)d_in[1];  // sdc_planning_gt (1,F,3)
    // d_in[2] = sdc_planning_gt_mask — unused by the reference
    const float* corners  = (const float*)d_in[3];  // future_gt_corners (F,N,4,2)
    const int*   mask     = (const int*)d_in[4];    // box_mask (F,N) bool -> int32
    float* partials       = (float*)d_ws;           // NBLOCKS * 4 B  (ws is re-poisoned, but we overwrite every slot)
    float* out            = (float*)d_out;

    CollisionLoss_55327768708655_kernel<<<NBLOCKS, BLOCK, 0, stream>>>(
        traj, gt, corners, mask, partials);
    finalize_kernel<<<1, BLOCK, 0, stream>>>(partials, out);
}